// Round 2
// baseline (1264.214 us; speedup 1.0000x reference)
//
#include <hip/hip_runtime.h>
#include <math.h>

#define NFEAT 512
#define NCLASSES 85742
#define NDEMOG 4
#define BATCH 512
#define S_VAL 64.0f
#define LAMBDA_REG 100.0f
#define LSE_SHIFT 64.0f

#define CB 32          // classes per block
#define KT 16          // k tile
#define NKT (NFEAT / KT)
#define NCBLK ((NCLASSES + CB - 1) / CB)

// ---------------- prep: normalize x (transposed to [k][n]), per-sample margin,
// zero sumexp accumulators, write temp outputs ----------------
__global__ void prep_kernel(const float* __restrict__ x,
                            const int* __restrict__ demog,
                            const float* __restrict__ margin,
                            float* __restrict__ xnT,
                            float* __restrict__ tlogit,
                            float* __restrict__ sumexp,
                            float* __restrict__ m_arr,
                            float* __restrict__ out) {
  const int n = blockIdx.x;
  const int lane = threadIdx.x;
  float v[8];
  const float* xr = x + n * NFEAT + lane * 8;
#pragma unroll
  for (int j = 0; j < 8; ++j) v[j] = xr[j];
  float s = 0.f;
#pragma unroll
  for (int j = 0; j < 8; ++j) s += v[j] * v[j];
#pragma unroll
  for (int off = 32; off >= 1; off >>= 1) s += __shfl_xor(s, off);
  const float inv = 1.f / fmaxf(sqrtf(s), 1e-12f);
#pragma unroll
  for (int j = 0; j < 8; ++j) xnT[(lane * 8 + j) * BATCH + n] = v[j] * inv;
  if (lane == 0) {
    m_arr[n] = expf(margin[demog[n]]);
    sumexp[n] = 0.f;
    tlogit[n] = 0.f;
  }
  if (n == 0 && lane < NDEMOG) out[1 + lane] = expf(margin[lane]);
}

// ---------------- main fused GEMM + partial sum-exp ----------------
// Block: 256 threads, tile = 512 samples x 32 classes, fp32 VALU, 8x8 per-thread.
// Fuses: w row-norm accumulation, margin at target class, exp(logit-64) partial sums.
__global__ __launch_bounds__(256) void gemm_kernel(
    const float* __restrict__ xnT,
    const float* __restrict__ w,
    const int* __restrict__ label,
    const float* __restrict__ m_arr,
    float* __restrict__ tlogit,
    float* __restrict__ sumexp) {
  __shared__ __align__(16) float x_s[KT][BATCH];
  __shared__ __align__(16) float w_s[KT][CB];
  __shared__ float wsq_s[CB][4];
  __shared__ float winv_s[CB];
  __shared__ float red_s[BATCH];

  const int tid = threadIdx.x;
  const int im = tid >> 2;      // 0..63 sample group
  const int ic = tid & 3;       // 0..3 class group
  const int n0 = im * 8;
  const int c0 = ic * 8;
  const int cbase = blockIdx.x * CB;

  float acc[8][8];
#pragma unroll
  for (int j = 0; j < 8; ++j)
#pragma unroll
    for (int q = 0; q < 8; ++q) acc[j][q] = 0.f;

  float wsq = 0.f;
  const int wc = tid >> 2;  // staging class (tid<128)
  const int wq = tid & 3;   // staging k-quarter

  for (int kt = 0; kt < NKT; ++kt) {
    __syncthreads();
    // stage x tile [KT][BATCH] (already normalized, already transposed)
#pragma unroll
    for (int i = 0; i < 8; ++i) {
      const int f4 = tid + 256 * i;
      const int kk = f4 >> 7;
      const int nq = (f4 & 127) << 2;
      const float4 vv = *(const float4*)&xnT[(kt * KT + kk) * BATCH + nq];
      *(float4*)&x_s[kk][nq] = vv;
    }
    // stage w tile (raw weights; accumulate squared norm on the fly)
    if (tid < CB * 4) {
      const int cg = cbase + wc;
      float4 vv = make_float4(0.f, 0.f, 0.f, 0.f);
      if (cg < NCLASSES)
        vv = *(const float4*)&w[cg * NFEAT + kt * KT + wq * 4];
      w_s[wq * 4 + 0][wc] = vv.x;
      w_s[wq * 4 + 1][wc] = vv.y;
      w_s[wq * 4 + 2][wc] = vv.z;
      w_s[wq * 4 + 3][wc] = vv.w;
      wsq += vv.x * vv.x + vv.y * vv.y + vv.z * vv.z + vv.w * vv.w;
    }
    __syncthreads();
#pragma unroll
    for (int kk = 0; kk < KT; ++kk) {
      float a[8], b[8];
      *(float4*)&a[0] = *(const float4*)&x_s[kk][n0];
      *(float4*)&a[4] = *(const float4*)&x_s[kk][n0 + 4];
      *(float4*)&b[0] = *(const float4*)&w_s[kk][c0];
      *(float4*)&b[4] = *(const float4*)&w_s[kk][c0 + 4];
#pragma unroll
      for (int j = 0; j < 8; ++j)
#pragma unroll
        for (int q = 0; q < 8; ++q)
          acc[j][q] = fmaf(a[j], b[q], acc[j][q]);
    }
  }

  // finish w norms
  if (tid < CB * 4) wsq_s[wc][wq] = wsq;
  __syncthreads();
  if (tid < CB) {
    const float ssum = wsq_s[tid][0] + wsq_s[tid][1] + wsq_s[tid][2] + wsq_s[tid][3];
    winv_s[tid] = 1.f / fmaxf(sqrtf(ssum), 1e-12f);
  }
  __syncthreads();

  int lbl[8];
  float mm[8], esum[8];
#pragma unroll
  for (int j = 0; j < 8; ++j) {
    lbl[j] = label[n0 + j];
    mm[j] = m_arr[n0 + j];
    esum[j] = 0.f;
  }
#pragma unroll
  for (int q = 0; q < 8; ++q) {
    const int cg = cbase + c0 + q;
    if (cg < NCLASSES) {
      const float winv = winv_s[c0 + q];
#pragma unroll
      for (int j = 0; j < 8; ++j) {
        float lg = S_VAL * acc[j][q] * winv;
        if (cg == lbl[j]) {
          lg -= S_VAL * mm[j];
          tlogit[n0 + j] = lg;  // unique writer across whole grid
        }
        esum[j] += __expf(lg - LSE_SHIFT);
      }
    }
  }

  // per-sample reduce across the 4 class-group threads, then one atomic each
  if (ic == 0) {
#pragma unroll
    for (int j = 0; j < 8; ++j) red_s[n0 + j] = esum[j];
  }
  __syncthreads();
  for (int s = 1; s < 4; ++s) {
    if (ic == s) {
#pragma unroll
      for (int j = 0; j < 8; ++j) red_s[n0 + j] += esum[j];
    }
    __syncthreads();
  }
  if (ic == 0) {
#pragma unroll
    for (int j = 0; j < 8; ++j) atomicAdd(&sumexp[n0 + j], red_s[n0 + j]);
  }
}

// ---------------- finalize: lse, CE mean, regularizer ----------------
__global__ void finalize_kernel(const float* __restrict__ tlogit,
                                const float* __restrict__ sumexp,
                                const float* __restrict__ margin,
                                float* __restrict__ out) {
  __shared__ float red[BATCH];
  const int tid = threadIdx.x;
  const float diff = (LSE_SHIFT + logf(sumexp[tid])) - tlogit[tid];
  red[tid] = diff;
  __syncthreads();
  for (int s = BATCH / 2; s >= 1; s >>= 1) {
    if (tid < s) red[tid] += red[tid + s];
    __syncthreads();
  }
  if (tid == 0) {
    float tmean = 0.f;
    for (int d = 0; d < NDEMOG; ++d) tmean += expf(margin[d]);
    tmean *= (1.f / NDEMOG);
    out[0] = red[0] * (1.f / BATCH) - LAMBDA_REG * tmean;
  }
}

extern "C" void kernel_launch(void* const* d_in, const int* in_sizes, int n_in,
                              void* d_out, int out_size, void* d_ws, size_t ws_size,
                              hipStream_t stream) {
  const float* x = (const float*)d_in[0];
  const int* label = (const int*)d_in[1];
  const int* demog = (const int*)d_in[2];
  const float* w = (const float*)d_in[3];
  const float* margin = (const float*)d_in[4];
  float* out = (float*)d_out;
  float* ws = (float*)d_ws;

  float* xnT = ws;                        // 512*512 floats (normalized x, [k][n])
  float* tl = ws + BATCH * NFEAT;         // 512 target logits
  float* se = tl + BATCH;                 // 512 sum-exp accumulators
  float* ma = se + BATCH;                 // 512 per-sample margins

  prep_kernel<<<BATCH, 64, 0, stream>>>(x, demog, margin, xnT, tl, se, ma, out);
  gemm_kernel<<<NCBLK, 256, 0, stream>>>(xnT, w, label, ma, tl, se);
  finalize_kernel<<<1, BATCH, 0, stream>>>(tl, se, margin, out);
}

// Round 8
// 369.833 us; speedup vs baseline: 3.4183x; 3.4183x over previous
//
#include <hip/hip_runtime.h>
#include <math.h>

#define NFEAT 512
#define NCLASSES 85742
#define NDEMOG 4
#define BATCH 512
#define S_VAL 64.0f
#define LAMBDA_REG 100.0f
#define L2E 1.4426950408889634f
#define SHIFT (64.0f * L2E)

#define BN 128                       // classes per block
#define KC 32                        // k per chunk
#define NCHUNK (NFEAT / KC)          // 16
#define NBLK ((NCLASSES + BN - 1) / BN)  // 670
#define THREADS 512
#define XCHUNK_BYTES (BATCH * 128)   // 64 KB: per row 64B hi + 64B lo

typedef short bf16x8 __attribute__((ext_vector_type(8)));
typedef float f32x4 __attribute__((ext_vector_type(4)));
typedef unsigned short ushort8v __attribute__((ext_vector_type(8)));

__device__ __forceinline__ unsigned short f2bf(float f) {
  unsigned u = __float_as_uint(f);
  u += 0x7fffu + ((u >> 16) & 1u);   // RNE
  return (unsigned short)(u >> 16);
}
__device__ __forceinline__ float bf2f(unsigned short h) {
  return __uint_as_float(((unsigned)h) << 16);
}

// ---------------- prep: normalize x, split to bf16 hi/lo, write the
// pre-swizzled LDS image (chunked [t][row][hi64|lo64], byte ^= (row&7)<<4).
// Also: per-sample margin, zero accumulators, temp outputs. ----------------
__global__ void prep_kernel(const float* __restrict__ x,
                            const int* __restrict__ demog,
                            const float* __restrict__ margin,
                            unsigned char* __restrict__ ximg,
                            float* __restrict__ tl, float* __restrict__ se,
                            float* __restrict__ ma, float* __restrict__ out) {
  const int n = blockIdx.x;
  const int l = threadIdx.x;  // 64
  const float* xr = x + (long)n * NFEAT + l * 8;
  float v[8];
#pragma unroll
  for (int j = 0; j < 8; ++j) v[j] = xr[j];
  float s = 0.f;
#pragma unroll
  for (int j = 0; j < 8; ++j) s = fmaf(v[j], v[j], s);
#pragma unroll
  for (int off = 32; off >= 1; off >>= 1) s += __shfl_xor(s, off);
  const float inv = 1.f / fmaxf(sqrtf(s), 1e-12f);

  ushort8v h, lo;
#pragma unroll
  for (int j = 0; j < 8; ++j) {
    const float f = v[j] * inv;
    const unsigned short hh = f2bf(f);
    h[j] = hh;
    lo[j] = f2bf(f - bf2f(hh));
  }
  // this lane's 8 k's = l*8..l*8+7 -> chunk t = l>>2, 16B slot kg = l&3
  const int t = l >> 2, kg = l & 3;
  const unsigned sw = (unsigned)((n & 7) << 4);
  const unsigned base = (unsigned)(n * 128 + kg * 16);
  *(ushort8v*)(ximg + t * XCHUNK_BYTES + (base ^ sw)) = h;
  *(ushort8v*)(ximg + t * XCHUNK_BYTES + ((base + 64u) ^ sw)) = lo;

  if (l == 0) { ma[n] = expf(margin[demog[n]]); se[n] = 0.f; tl[n] = 0.f; }
  if (n == 0 && l < NDEMOG) out[1 + l] = expf(margin[l]);
}

// ---------------- main MFMA GEMM, tile 512x128, 8 waves, K dbuf ----------------
__global__ __launch_bounds__(THREADS) void gemm_kernel(
    const unsigned char* __restrict__ ximg, const float* __restrict__ w,
    const int* __restrict__ label, const float* __restrict__ ma,
    float* __restrict__ tl, float* __restrict__ se) {
  __shared__ __align__(16) unsigned char xs0[2 * XCHUNK_BYTES];  // 128 KB
  __shared__ __align__(16) unsigned char wsb[2 * BN * 64];       // 16 KB
  __shared__ float wsq_s[BN * 4];
  __shared__ float winv_s[BN];

  const int tid = threadIdx.x;
  const int wv = tid >> 6;
  const int l = tid & 63;
  const int lh = l >> 4, ll = l & 15;
  const long cbase = (long)blockIdx.x * BN;

  f32x4 acc[4][8];
#pragma unroll
  for (int m = 0; m < 4; ++m)
#pragma unroll
    for (int n = 0; n < 8; ++n) acc[m][n] = (f32x4){0.f, 0.f, 0.f, 0.f};

  // w staging assignment: thread -> (class sc, k-octet skg)
  const int sc = tid >> 2, skg = tid & 3;
  const bool wvalid = (cbase + sc) < NCLASSES;
  const float* wrow = w + (cbase + sc) * (long)NFEAT + skg * 8;
  const unsigned wdst = ((unsigned)(sc * 64 + skg * 16)) ^ ((unsigned)((sc & 7) << 4));
  float wsq = 0.f;

  // fragment LDS offsets (row&7 == ll&7 for all A rows and B rows)
  const unsigned swA = (unsigned)((ll & 7) << 4);
  unsigned aoff[4][2], boff[8];
#pragma unroll
  for (int m = 0; m < 4; ++m) {
    const unsigned r = (unsigned)(wv * 64 + m * 16 + ll);
    aoff[m][0] = (r * 128u + (unsigned)(lh * 16)) ^ swA;
    aoff[m][1] = (r * 128u + 64u + (unsigned)(lh * 16)) ^ swA;
  }
#pragma unroll
  for (int n = 0; n < 8; ++n) {
    const unsigned cr = (unsigned)(n * 16 + ll);
    boff[n] = (cr * 64u + (unsigned)(lh * 16)) ^ swA;
  }

  // ---- prologue: stage chunk 0 into buffer 0
  {
    const unsigned char* src = ximg + wv * 8192 + l * 16;
#pragma unroll
    for (int i = 0; i < 8; ++i)
      __builtin_amdgcn_global_load_lds(
          (const __attribute__((address_space(1))) unsigned int*)(src + i * 1024),
          (__attribute__((address_space(3))) unsigned int*)(xs0 + wv * 8192 + i * 1024),
          16, 0, 0);
    float4 wa = make_float4(0.f, 0.f, 0.f, 0.f), wb = wa;
    if (wvalid) { wa = *(const float4*)wrow; wb = *(const float4*)(wrow + 4); }
    wsq += wa.x * wa.x + wa.y * wa.y + wa.z * wa.z + wa.w * wa.w +
           wb.x * wb.x + wb.y * wb.y + wb.z * wb.z + wb.w * wb.w;
    ushort8v u;
    u[0] = f2bf(wa.x); u[1] = f2bf(wa.y); u[2] = f2bf(wa.z); u[3] = f2bf(wa.w);
    u[4] = f2bf(wb.x); u[5] = f2bf(wb.y); u[6] = f2bf(wb.z); u[7] = f2bf(wb.w);
    *(ushort8v*)&wsb[wdst] = u;
  }
  __syncthreads();

  // ---- main loop
  for (int t = 0; t < NCHUNK; ++t) {
    const int cur = t & 1, nxt = cur ^ 1;
    const unsigned char* xcur = xs0 + cur * XCHUNK_BYTES;
    const unsigned char* wcur = wsb + cur * (BN * 64);
    float4 wa = make_float4(0.f, 0.f, 0.f, 0.f), wb = wa;
    const bool pf = (t + 1 < NCHUNK);
    if (pf) {
      const unsigned char* src = ximg + (t + 1) * XCHUNK_BYTES + wv * 8192 + l * 16;
      unsigned char* dstb = xs0 + nxt * XCHUNK_BYTES + wv * 8192;
#pragma unroll
      for (int i = 0; i < 8; ++i)
        __builtin_amdgcn_global_load_lds(
            (const __attribute__((address_space(1))) unsigned int*)(src + i * 1024),
            (__attribute__((address_space(3))) unsigned int*)(dstb + i * 1024),
            16, 0, 0);
      if (wvalid) {
        wa = *(const float4*)(wrow + (t + 1) * KC);
        wb = *(const float4*)(wrow + (t + 1) * KC + 4);
      }
    }
    // compute chunk t
    bf16x8 b[8];
#pragma unroll
    for (int n = 0; n < 8; ++n) b[n] = *(const bf16x8*)&wcur[boff[n]];
#pragma unroll
    for (int m = 0; m < 4; ++m) {
      const bf16x8 ah = *(const bf16x8*)&xcur[aoff[m][0]];
      const bf16x8 al = *(const bf16x8*)&xcur[aoff[m][1]];
#pragma unroll
      for (int n = 0; n < 8; ++n)
        acc[m][n] = __builtin_amdgcn_mfma_f32_16x16x32_bf16(ah, b[n], acc[m][n], 0, 0, 0);
#pragma unroll
      for (int n = 0; n < 8; ++n)
        acc[m][n] = __builtin_amdgcn_mfma_f32_16x16x32_bf16(al, b[n], acc[m][n], 0, 0, 0);
    }
    if (pf) {
      wsq += wa.x * wa.x + wa.y * wa.y + wa.z * wa.z + wa.w * wa.w +
             wb.x * wb.x + wb.y * wb.y + wb.z * wb.z + wb.w * wb.w;
      ushort8v u;
      u[0] = f2bf(wa.x); u[1] = f2bf(wa.y); u[2] = f2bf(wa.z); u[3] = f2bf(wa.w);
      u[4] = f2bf(wb.x); u[5] = f2bf(wb.y); u[6] = f2bf(wb.z); u[7] = f2bf(wb.w);
      *(ushort8v*)&wsb[nxt * (BN * 64) + wdst] = u;
    }
    __syncthreads();
  }

  // ---- w norms
  wsq_s[sc * 4 + skg] = wsq;
  __syncthreads();
  if (tid < BN) {
    const float ss = wsq_s[tid * 4 + 0] + wsq_s[tid * 4 + 1] +
                     wsq_s[tid * 4 + 2] + wsq_s[tid * 4 + 3];
    winv_s[tid] = 1.f / fmaxf(sqrtf(ss), 1e-12f);
  }
  __syncthreads();

  // ---- epilogue: logits -> partial sum-exp (fixed shift 64), margin at target
  int lbls[16];
  float ps[16];
#pragma unroll
  for (int m = 0; m < 4; ++m)
#pragma unroll
    for (int q = 0; q < 4; ++q) {
      const int r = wv * 64 + m * 16 + lh * 4 + q;
      lbls[m * 4 + q] = label[r];
      ps[m * 4 + q] = 0.f;
    }
#pragma unroll
  for (int n = 0; n < 8; ++n) {
    const int c = (int)cbase + n * 16 + ll;
    const float wvv = winv_s[n * 16 + ll];
    const float an = S_VAL * L2E * wvv;
#pragma unroll
    for (int m = 0; m < 4; ++m)
#pragma unroll
      for (int q = 0; q < 4; ++q) {
        const float a = acc[m][n][q];
        float e;
        if (c == lbls[m * 4 + q]) {
          const int r = wv * 64 + m * 16 + lh * 4 + q;
          const float lgt = S_VAL * fmaf(a, wvv, -ma[r]);
          tl[r] = lgt;
          e = exp2f((lgt - 64.f) * L2E);
        } else {
          e = exp2f(fmaf(a, an, -SHIFT));
        }
        ps[m * 4 + q] += e;
      }
  }
#pragma unroll
  for (int k = 0; k < 16; ++k) {
    float vsum = ps[k];
    vsum += __shfl_xor(vsum, 1);
    vsum += __shfl_xor(vsum, 2);
    vsum += __shfl_xor(vsum, 4);
    vsum += __shfl_xor(vsum, 8);
    if (ll == 0) {
      const int r = wv * 64 + (k >> 2) * 16 + lh * 4 + (k & 3);
      atomicAdd(&se[r], vsum);
    }
  }
}

// ---------------- finalize ----------------
__global__ void finalize_kernel(const float* __restrict__ tl,
                                const float* __restrict__ se,
                                const float* __restrict__ margin,
                                float* __restrict__ out) {
  __shared__ float red[BATCH];
  const int tid = threadIdx.x;
  red[tid] = (64.f + logf(se[tid])) - tl[tid];
  __syncthreads();
  for (int s = BATCH / 2; s >= 1; s >>= 1) {
    if (tid < s) red[tid] += red[tid + s];
    __syncthreads();
  }
  if (tid == 0) {
    float tmean = 0.f;
    for (int d = 0; d < NDEMOG; ++d) tmean += expf(margin[d]);
    tmean *= (1.f / NDEMOG);
    out[0] = red[0] * (1.f / BATCH) - LAMBDA_REG * tmean;
  }
}

extern "C" void kernel_launch(void* const* d_in, const int* in_sizes, int n_in,
                              void* d_out, int out_size, void* d_ws, size_t ws_size,
                              hipStream_t stream) {
  const float* x = (const float*)d_in[0];
  const int* label = (const int*)d_in[1];
  const int* demog = (const int*)d_in[2];
  const float* w = (const float*)d_in[3];
  const float* margin = (const float*)d_in[4];
  float* out = (float*)d_out;
  unsigned char* ws = (unsigned char*)d_ws;

  unsigned char* ximg = ws;                       // 16 * 64KB = 1 MB
  float* tl = (float*)(ws + 16 * XCHUNK_BYTES);   // 512
  float* se = tl + BATCH;                         // 512
  float* ma = se + BATCH;                         // 512

  prep_kernel<<<BATCH, 64, 0, stream>>>(x, demog, margin, ximg, tl, se, ma, out);
  gemm_kernel<<<NBLK, THREADS, 0, stream>>>(ximg, w, label, ma, tl, se);
  finalize_kernel<<<1, BATCH, 0, stream>>>(tl, se, margin, out);
}